// Round 2
// baseline (269.266 us; speedup 1.0000x reference)
//
#include <hip/hip_runtime.h>
#include <stdint.h>

#define NB 8
#define NP 12000
#define NM 32
#define NF 9
#define NC 64
#define NX 144
#define NCELL (144*144)
#define CH 16          // channels per register chunk (4 chunks of 16)
#define NQ 4           // m-quarters per pillar (one thread each)
#define MQ (NM/NQ)     // 8 m-rows per thread

// Pass 1: last-write-wins resolution. numpy fancy assignment semantics:
// for duplicate cells the LAST pillar (largest p) wins -> atomicMax on p.
__global__ void winner_kernel(const int* __restrict__ idx, int* __restrict__ winner) {
    int t = blockIdx.x * blockDim.x + threadIdx.x;
    if (t >= NB * NP) return;
    int b = t / NP;
    int p = t - b * NP;
    int y = idx[t * 3 + 1];
    int x = idx[t * 3 + 2];
    x = x < 0 ? 0 : (x > 143 ? 143 : x);
    y = y < 0 ? 0 : (y > 143 ? 143 : y);
    int cell = y * NX + x;
    atomicMax(&winner[b * NCELL + cell], p);   // winner init = -1 (memset 0xFF)
}

// Pass 2: conv(K=9) + BN(folded into weights) + ReLU + max over m, scatter.
// thread = (pillar, m-quarter). BN scale folded into weights so the inner
// loop is 9 FMA + 1 max per (m, channel); shift+ReLU applied once at the end
// (shift is m-invariant; relu monotone -> both commute with max over m).
__global__ void __launch_bounds__(256, 2) feat_kernel(
    const float* __restrict__ pillars,
    const int*   __restrict__ idx,
    const float* __restrict__ conv_w,
    const float* __restrict__ gamma,
    const float* __restrict__ beta,
    const float* __restrict__ mean,
    const float* __restrict__ var,
    const int*   __restrict__ winner,
    float* __restrict__ out)
{
    int t = blockIdx.x * blockDim.x + threadIdx.x;   // [0, NB*NP*NQ)
    if (t >= NB * NP * NQ) return;
    int q   = t & (NQ - 1);
    int pil = t >> 2;                 // global pillar id
    int b   = pil / NP;
    int p   = pil - b * NP;

    int y = idx[pil * 3 + 1];
    int x = idx[pil * 3 + 2];
    x = x < 0 ? 0 : (x > 143 ? 143 : x);
    y = y < 0 ? 0 : (y > 143 ? 143 : y);
    int cell = y * NX + x;

    // All 4 quarter-threads of a losing pillar exit together (no shfl hazard).
    if (winner[b * NCELL + cell] != p) return;
    bool do_store = (q == 0);

    const float* prow = pillars + (long long)pil * (NM * NF) + q * (MQ * NF);

    for (int c0 = 0; c0 < NC; c0 += CH) {
        float w[CH][NF];
        float shift[CH];
        #pragma unroll
        for (int j = 0; j < CH; ++j) {
            int c = c0 + j;
            float sc = gamma[c] * rsqrtf(var[c] + 1e-5f);
            shift[j] = beta[c] - mean[c] * sc;
            #pragma unroll
            for (int f = 0; f < NF; ++f) w[j][f] = conv_w[c * NF + f] * sc;
        }
        float mx[CH];
        #pragma unroll
        for (int j = 0; j < CH; ++j) mx[j] = -1e30f;

        #pragma unroll
        for (int m = 0; m < MQ; ++m) {
            float r[NF];
            #pragma unroll
            for (int f = 0; f < NF; ++f) r[f] = prow[m * NF + f];
            #pragma unroll
            for (int j = 0; j < CH; ++j) {
                float acc = r[0] * w[j][0];
                #pragma unroll
                for (int f = 1; f < NF; ++f) acc = fmaf(r[f], w[j][f], acc);
                mx[j] = fmaxf(mx[j], acc);
            }
        }
        // max-reduce the 4 m-quarters (lanes 4k..4k+3, never crossing a wave)
        #pragma unroll
        for (int j = 0; j < CH; ++j) {
            mx[j] = fmaxf(mx[j], __shfl_xor(mx[j], 1));
            mx[j] = fmaxf(mx[j], __shfl_xor(mx[j], 2));
        }
        if (do_store) {
            #pragma unroll
            for (int j = 0; j < CH; ++j) {
                float v = mx[j] + shift[j];
                out[((long long)(b * NC + c0 + j)) * NCELL + cell] = v > 0.f ? v : 0.f;
            }
        }
    }
}

extern "C" void kernel_launch(void* const* d_in, const int* in_sizes, int n_in,
                              void* d_out, int out_size, void* d_ws, size_t ws_size,
                              hipStream_t stream) {
    const float* pillars = (const float*)d_in[0];
    const int*   idx     = (const int*)d_in[1];
    const float* conv_w  = (const float*)d_in[2];
    const float* gamma   = (const float*)d_in[3];
    const float* beta    = (const float*)d_in[4];
    const float* mean    = (const float*)d_in[5];
    const float* var     = (const float*)d_in[6];
    float* out = (float*)d_out;
    int* winner = (int*)d_ws;                       // NB*NCELL ints = 663,552 B

    // winner = -1 everywhere; output canvas = 0 (harness poisons with 0xAA)
    hipMemsetAsync(winner, 0xFF, (size_t)NB * NCELL * sizeof(int), stream);
    hipMemsetAsync(out, 0, (size_t)out_size * sizeof(float), stream);

    {
        int threads = NB * NP;
        winner_kernel<<<(threads + 255) / 256, 256, 0, stream>>>(idx, winner);
    }
    {
        int threads = NB * NP * NQ;
        feat_kernel<<<(threads + 255) / 256, 256, 0, stream>>>(
            pillars, idx, conv_w, gamma, beta, mean, var, winner, out);
    }
}

// Round 3
// 246.502 us; speedup vs baseline: 1.0924x; 1.0924x over previous
//
#include <hip/hip_runtime.h>
#include <stdint.h>

#define NB 8
#define NP 12000
#define NM 32
#define NF 9
#define NC 64
#define NX 144
#define NCELL (144*144)
#define NCG 8          // channel-groups per pillar (threads/pillar)
#define CH (NC/NCG)    // 8 channels per thread
#define WSTRIDE 12     // padded folded-weight row stride (float4-friendly)

// ws layout (compact path):
//   [0,      3072)   folded weights wf[c*12+f] (64x12 floats)
//   [3072,   3328)   shift[c] (64 floats)
//   [4096,   667648) winner[b][cell] (8*20736 ints)
//   [668672, +24.576M) feat_ws[(b*NP+p)*64 + c]
#define WS_WF_OFF     0
#define WS_SHIFT_OFF  3072
#define WS_WIN_OFF    4096
#define WS_FEAT_OFF   668672
#define WS_NEED       (WS_FEAT_OFF + (size_t)NB*NP*NC*4)

// Fold BN into weights once: wf = w*gamma*rsqrt(var+eps), shift = beta - mean*scale
__global__ void prep_kernel(const float* __restrict__ conv_w,
                            const float* __restrict__ gamma,
                            const float* __restrict__ beta,
                            const float* __restrict__ mean,
                            const float* __restrict__ var,
                            float* __restrict__ wf, float* __restrict__ shift) {
    int c = threadIdx.x;
    if (c >= NC) return;
    float sc = gamma[c] * rsqrtf(var[c] + 1e-5f);
    shift[c] = beta[c] - mean[c] * sc;
    #pragma unroll
    for (int f = 0; f < NF; ++f) wf[c * WSTRIDE + f] = conv_w[c * NF + f] * sc;
    #pragma unroll
    for (int f = NF; f < WSTRIDE; ++f) wf[c * WSTRIDE + f] = 0.f;
}

// Last-write-wins: numpy fancy assignment -> largest pillar index p wins.
__global__ void winner_kernel(const int* __restrict__ idx, int* __restrict__ winner) {
    int t = blockIdx.x * blockDim.x + threadIdx.x;
    if (t >= NB * NP) return;
    int b = t / NP;
    int p = t - b * NP;
    int y = idx[t * 3 + 1];
    int x = idx[t * 3 + 2];
    x = x < 0 ? 0 : (x > 143 ? 143 : x);
    y = y < 0 ? 0 : (y > 143 ? 143 : y);
    atomicMax(&winner[b * NCELL + y * NX + x], p);   // init = -1
}

// thread = (pillar, 8-channel group). Weights loaded ONCE from folded table.
// COMPACT: write feat contiguously to ws; else scatter directly to out.
template <bool COMPACT>
__global__ void __launch_bounds__(256, 3) feat_kernel(
    const float* __restrict__ pillars,
    const int*   __restrict__ idx,
    const float* __restrict__ wf,
    const float* __restrict__ shift,
    const int*   __restrict__ winner,
    float* __restrict__ feat_ws,
    float* __restrict__ out)
{
    int t = blockIdx.x * blockDim.x + threadIdx.x;   // [0, NB*NP*NCG)
    if (t >= NB * NP * NCG) return;
    int cg  = t & (NCG - 1);
    int pil = t >> 3;
    int b   = pil / NP;
    int p   = pil - b * NP;

    int y = idx[pil * 3 + 1];
    int x = idx[pil * 3 + 2];
    x = x < 0 ? 0 : (x > 143 ? 143 : x);
    y = y < 0 ? 0 : (y > 143 ? 143 : y);
    int cell = y * NX + x;
    if (winner[b * NCELL + cell] != p) return;       // loser pillar

    // 8 channels x 9 folded weights, via aligned float4 (stride 12 floats = 48B)
    float w[CH][NF];
    float sh[CH];
    {
        const float4* wf4 = (const float4*)wf;
        #pragma unroll
        for (int j = 0; j < CH; ++j) {
            int c = cg * CH + j;
            float4 a = wf4[c * 3 + 0], bq = wf4[c * 3 + 1], cq = wf4[c * 3 + 2];
            w[j][0]=a.x; w[j][1]=a.y; w[j][2]=a.z; w[j][3]=a.w;
            w[j][4]=bq.x; w[j][5]=bq.y; w[j][6]=bq.z; w[j][7]=bq.w;
            w[j][8]=cq.x;
            sh[j] = shift[c];
        }
    }

    float mx[CH];
    #pragma unroll
    for (int j = 0; j < CH; ++j) mx[j] = -1e30f;

    // pillar block: 32*9 = 288 contiguous floats; process 4 m-rows (36 floats,
    // 144B-aligned) per step via 9 float4 loads.
    const float4* p4 = (const float4*)(pillars + (long long)pil * (NM * NF));
    #pragma unroll 2
    for (int s = 0; s < NM / 4; ++s) {
        float buf[36];
        #pragma unroll
        for (int k = 0; k < 9; ++k) {
            float4 v = p4[s * 9 + k];
            buf[k*4+0]=v.x; buf[k*4+1]=v.y; buf[k*4+2]=v.z; buf[k*4+3]=v.w;
        }
        #pragma unroll
        for (int mm = 0; mm < 4; ++mm) {
            #pragma unroll
            for (int j = 0; j < CH; ++j) {
                float acc = buf[mm*NF] * w[j][0];
                #pragma unroll
                for (int f = 1; f < NF; ++f) acc = fmaf(buf[mm*NF+f], w[j][f], acc);
                mx[j] = fmaxf(mx[j], acc);
            }
        }
    }

    float v[CH];
    #pragma unroll
    for (int j = 0; j < CH; ++j) {
        float r = mx[j] + sh[j];
        v[j] = r > 0.f ? r : 0.f;
    }

    if (COMPACT) {
        float4* dst = (float4*)(feat_ws + (long long)pil * NC + cg * CH);
        dst[0] = make_float4(v[0], v[1], v[2], v[3]);
        dst[1] = make_float4(v[4], v[5], v[6], v[7]);
    } else {
        #pragma unroll
        for (int j = 0; j < CH; ++j)
            out[((long long)(b * NC + cg * CH + j)) * NCELL + cell] = v[j];
    }
}

// Cell-major coalesced canvas write. thread = (b, 4 consecutive cells).
// Reads feat via 16B gathers (LLC-hot), writes float4 per c-plane (coalesced).
__global__ void scatter_kernel(const int* __restrict__ winner,
                               const float* __restrict__ feat_ws,
                               float* __restrict__ out)
{
    int t = blockIdx.x * blockDim.x + threadIdx.x;   // [0, NB*NCELL/4)
    if (t >= NB * (NCELL / 4)) return;
    int b  = t / (NCELL / 4);
    int c4 = t - b * (NCELL / 4);
    int cellbase = c4 * 4;

    int4 wv = *(const int4*)(winner + b * NCELL + cellbase);
    long long base0 = wv.x < 0 ? -1 : ((long long)(b * NP + wv.x)) * NC;
    long long base1 = wv.y < 0 ? -1 : ((long long)(b * NP + wv.y)) * NC;
    long long base2 = wv.z < 0 ? -1 : ((long long)(b * NP + wv.z)) * NC;
    long long base3 = wv.w < 0 ? -1 : ((long long)(b * NP + wv.w)) * NC;

    const float4 z = make_float4(0.f, 0.f, 0.f, 0.f);
    #pragma unroll 4
    for (int c0 = 0; c0 < NC; c0 += 4) {
        float4 f0 = base0 < 0 ? z : *(const float4*)(feat_ws + base0 + c0);
        float4 f1 = base1 < 0 ? z : *(const float4*)(feat_ws + base1 + c0);
        float4 f2 = base2 < 0 ? z : *(const float4*)(feat_ws + base2 + c0);
        float4 f3 = base3 < 0 ? z : *(const float4*)(feat_ws + base3 + c0);
        float* o = out + ((long long)(b * NC + c0)) * NCELL + cellbase;
        *(float4*)(o + 0LL*NCELL) = make_float4(f0.x, f1.x, f2.x, f3.x);
        *(float4*)(o + 1LL*NCELL) = make_float4(f0.y, f1.y, f2.y, f3.y);
        *(float4*)(o + 2LL*NCELL) = make_float4(f0.z, f1.z, f2.z, f3.z);
        *(float4*)(o + 3LL*NCELL) = make_float4(f0.w, f1.w, f2.w, f3.w);
    }
}

extern "C" void kernel_launch(void* const* d_in, const int* in_sizes, int n_in,
                              void* d_out, int out_size, void* d_ws, size_t ws_size,
                              hipStream_t stream) {
    const float* pillars = (const float*)d_in[0];
    const int*   idx     = (const int*)d_in[1];
    const float* conv_w  = (const float*)d_in[2];
    const float* gamma   = (const float*)d_in[3];
    const float* beta    = (const float*)d_in[4];
    const float* mean    = (const float*)d_in[5];
    const float* var     = (const float*)d_in[6];
    float* out = (float*)d_out;

    char* ws = (char*)d_ws;
    float* wf      = (float*)(ws + WS_WF_OFF);
    float* shift   = (float*)(ws + WS_SHIFT_OFF);
    int*   winner  = (int*)  (ws + WS_WIN_OFF);
    float* feat_ws = (float*)(ws + WS_FEAT_OFF);

    const bool compact = ws_size >= WS_NEED;   // constant per session -> graph-safe

    hipMemsetAsync(winner, 0xFF, (size_t)NB * NCELL * sizeof(int), stream);
    prep_kernel<<<1, 64, 0, stream>>>(conv_w, gamma, beta, mean, var, wf, shift);
    winner_kernel<<<(NB * NP + 255) / 256, 256, 0, stream>>>(idx, winner);

    int fthreads = NB * NP * NCG;
    if (compact) {
        feat_kernel<true><<<(fthreads + 255) / 256, 256, 0, stream>>>(
            pillars, idx, wf, shift, winner, feat_ws, out);
        int sthreads = NB * (NCELL / 4);
        scatter_kernel<<<(sthreads + 255) / 256, 256, 0, stream>>>(winner, feat_ws, out);
    } else {
        hipMemsetAsync(out, 0, (size_t)out_size * sizeof(float), stream);
        feat_kernel<false><<<(fthreads + 255) / 256, 256, 0, stream>>>(
            pillars, idx, wf, shift, winner, feat_ws, out);
    }
}

// Round 4
// 211.041 us; speedup vs baseline: 1.2759x; 1.1680x over previous
//
#include <hip/hip_runtime.h>
#include <hip/hip_bf16.h>
#include <stdint.h>

#define NB 8
#define NP 12000
#define NM 32
#define NF 9
#define NC 64
#define NX 144
#define NCELL (144*144)

#define PCHUNK 16                    // pillars per block
#define NCHUNK ((NB*NP)/PCHUNK)      // 6000 blocks (12000%16==0 -> no batch straddle)

typedef __attribute__((ext_vector_type(8)))  short bfrag8;    // 8 bf16 (4 VGPR)
typedef __attribute__((ext_vector_type(16))) float accf16;    // 16 f32 acc

// ws layout:
//   [0,2048)        btab: 2 c-tiles x 64 lanes x 8 bf16 (B-frag order, BN-folded)
//   [2048,2304)     shift[c]
//   [4096,667648)   winner[b][cell]
//   [668672, +24.576M) feat_ws[(b*NP+p)*64 + c]
#define WS_BTAB  0
#define WS_SHIFT 2048
#define WS_WIN   4096
#define WS_FEAT  668672
#define WS_NEED  (WS_FEAT + (size_t)NB*NP*NC*4)

// Pass 1: last-write-wins (largest p wins) + weight prep in block 0.
// btab[ct][lane] = B-frag: B[k=(lane>>5)*8+j][col=lane&31], c = ct*32+col,
// weights pre-scaled by gamma*rsqrt(var+eps); k>=9 zero-padded.
__global__ void winner_prep_kernel(const int* __restrict__ idx, int* __restrict__ winner,
                                   const float* __restrict__ conv_w,
                                   const float* __restrict__ gamma,
                                   const float* __restrict__ beta,
                                   const float* __restrict__ mean,
                                   const float* __restrict__ var,
                                   unsigned short* __restrict__ btab,
                                   float* __restrict__ shift)
{
    int t = blockIdx.x * blockDim.x + threadIdx.x;
    if (t < NB * NP) {
        int b = t / NP;
        int p = t - b * NP;
        int y = idx[t * 3 + 1];
        int x = idx[t * 3 + 2];
        x = x < 0 ? 0 : (x > 143 ? 143 : x);
        y = y < 0 ? 0 : (y > 143 ? 143 : y);
        atomicMax(&winner[b * NCELL + y * NX + x], p);
    }
    if (blockIdx.x == 0) {
        int tt = threadIdx.x;
        if (tt < 128) {
            int ct = tt >> 6, L = tt & 63;
            int c  = ct * 32 + (L & 31);
            int kq = L >> 5;
            float sc = gamma[c] * rsqrtf(var[c] + 1e-5f);
            unsigned short* dst = btab + (ct * 64 + L) * 8;
            #pragma unroll
            for (int j = 0; j < 8; ++j) {
                int k = kq * 8 + j;
                float w = (k < NF) ? conv_w[c * NF + k] * sc : 0.f;
                __hip_bfloat16 h = __float2bfloat16(w);
                dst[j] = *(unsigned short*)&h;
            }
        }
        if (tt < NC) {
            float sc = gamma[tt] * rsqrtf(var[tt] + 1e-5f);
            shift[tt] = beta[tt] - mean[tt] * sc;
        }
    }
}

// Pass 2: MFMA conv+max. Block stages 16 pillars (32 rows x 9 f) as bf16 into
// LDS padded to row-stride 16 halfwords (k=9..15 zero). Each wave computes 4
// pillars: 1 ds_read_b128 A-frag + 2 v_mfma_f32_32x32x16_bf16 (c-tiles of 32),
// max over m via 15 reg-max + shfl_xor(32), then BN shift + relu; lane ==
// output channel -> 256B coalesced store.
template <bool COMPACT>
__global__ void __launch_bounds__(256) feat_mfma_kernel(
    const float* __restrict__ pillars,
    const int*   __restrict__ idx,
    const unsigned short* __restrict__ btab,
    const float* __restrict__ shift,
    const int*   __restrict__ winner,
    float* __restrict__ feat_ws,
    float* __restrict__ out)
{
    __shared__ unsigned short tile[PCHUNK * NM * 16];   // 16 KB
    int tid  = threadIdx.x;
    int lane = tid & 63;
    int wave = tid >> 6;
    int chunk = blockIdx.x;

    // zero the k=9..15 pad slots (disjoint from data slots -> no barrier needed)
    #pragma unroll
    for (int rr = 0; rr < 2; ++rr) {
        int r = tid + rr * 256;                     // 512 rows total
        tile[r * 16 + 9] = 0;
        *(unsigned int*)&tile[r * 16 + 10] = 0;
        *(unsigned int*)&tile[r * 16 + 12] = 0;
        *(unsigned int*)&tile[r * 16 + 14] = 0;
    }
    // stage 16 pillars = 4608 floats = 2304 float2 (coalesced), cvt to bf16
    const float2* src = (const float2*)(pillars + (long long)chunk * (PCHUNK * NM * NF));
    #pragma unroll
    for (int i = 0; i < 9; ++i) {
        int le2 = tid + i * 256;                    // exactly 2304 = 9*256
        float2 v = src[le2];
        int le = le2 * 2;
        int r = le / 9;
        int f = le - r * 9;
        __hip_bfloat16 hx = __float2bfloat16(v.x);
        tile[r * 16 + f] = *(unsigned short*)&hx;
        int f2 = f + 1, r2 = r;
        if (f2 == 9) { f2 = 0; r2 = r + 1; }
        __hip_bfloat16 hy = __float2bfloat16(v.y);
        tile[r2 * 16 + f2] = *(unsigned short*)&hy;
    }
    __syncthreads();

    bfrag8 b0 = *(const bfrag8*)(btab + lane * 8);          // c-tile 0 (c 0..31)
    bfrag8 b1 = *(const bfrag8*)(btab + (64 + lane) * 8);   // c-tile 1 (c 32..63)
    float  sh = shift[lane];

    int row = lane & 31;
    int kq  = lane >> 5;

    #pragma unroll
    for (int i = 0; i < 4; ++i) {
        int pr  = wave * 4 + i;
        int pil = chunk * PCHUNK + pr;
        int b   = pil / NP;
        int p   = pil - b * NP;
        int y = idx[pil * 3 + 1];
        int x = idx[pil * 3 + 2];
        x = x < 0 ? 0 : (x > 143 ? 143 : x);
        y = y < 0 ? 0 : (y > 143 ? 143 : y);
        int cell = y * NX + x;
        if (winner[b * NCELL + cell] != p) continue;   // wave-uniform skip

        bfrag8 a = *(const bfrag8*)&tile[pr * 512 + row * 16 + kq * 8];
        accf16 z = (accf16)0.0f;
        accf16 acc0 = __builtin_amdgcn_mfma_f32_32x32x16_bf16(a, b0, z, 0, 0, 0);
        accf16 acc1 = __builtin_amdgcn_mfma_f32_32x32x16_bf16(a, b1, z, 0, 0, 0);

        float v0 = acc0[0], v1 = acc1[0];
        #pragma unroll
        for (int j = 1; j < 16; ++j) { v0 = fmaxf(v0, acc0[j]); v1 = fmaxf(v1, acc1[j]); }
        v0 = fmaxf(v0, __shfl_xor(v0, 32));
        v1 = fmaxf(v1, __shfl_xor(v1, 32));
        float r = (lane < 32) ? v0 : v1;     // col = lane&31 -> channel = lane
        r = r + sh;
        r = r > 0.f ? r : 0.f;

        if (COMPACT) {
            feat_ws[(long long)pil * NC + lane] = r;
        } else {
            out[((long long)(b * NC + lane)) * NCELL + cell] = r;
        }
    }
}

// Cell-major coalesced canvas write (unchanged from R3).
__global__ void scatter_kernel(const int* __restrict__ winner,
                               const float* __restrict__ feat_ws,
                               float* __restrict__ out)
{
    int t = blockIdx.x * blockDim.x + threadIdx.x;
    if (t >= NB * (NCELL / 4)) return;
    int b  = t / (NCELL / 4);
    int c4 = t - b * (NCELL / 4);
    int cellbase = c4 * 4;

    int4 wv = *(const int4*)(winner + b * NCELL + cellbase);
    long long base0 = wv.x < 0 ? -1 : ((long long)(b * NP + wv.x)) * NC;
    long long base1 = wv.y < 0 ? -1 : ((long long)(b * NP + wv.y)) * NC;
    long long base2 = wv.z < 0 ? -1 : ((long long)(b * NP + wv.z)) * NC;
    long long base3 = wv.w < 0 ? -1 : ((long long)(b * NP + wv.w)) * NC;

    const float4 z = make_float4(0.f, 0.f, 0.f, 0.f);
    #pragma unroll 4
    for (int c0 = 0; c0 < NC; c0 += 4) {
        float4 f0 = base0 < 0 ? z : *(const float4*)(feat_ws + base0 + c0);
        float4 f1 = base1 < 0 ? z : *(const float4*)(feat_ws + base1 + c0);
        float4 f2 = base2 < 0 ? z : *(const float4*)(feat_ws + base2 + c0);
        float4 f3 = base3 < 0 ? z : *(const float4*)(feat_ws + base3 + c0);
        float* o = out + ((long long)(b * NC + c0)) * NCELL + cellbase;
        *(float4*)(o + 0LL * NCELL) = make_float4(f0.x, f1.x, f2.x, f3.x);
        *(float4*)(o + 1LL * NCELL) = make_float4(f0.y, f1.y, f2.y, f3.y);
        *(float4*)(o + 2LL * NCELL) = make_float4(f0.z, f1.z, f2.z, f3.z);
        *(float4*)(o + 3LL * NCELL) = make_float4(f0.w, f1.w, f2.w, f3.w);
    }
}

extern "C" void kernel_launch(void* const* d_in, const int* in_sizes, int n_in,
                              void* d_out, int out_size, void* d_ws, size_t ws_size,
                              hipStream_t stream) {
    const float* pillars = (const float*)d_in[0];
    const int*   idx     = (const int*)d_in[1];
    const float* conv_w  = (const float*)d_in[2];
    const float* gamma   = (const float*)d_in[3];
    const float* beta    = (const float*)d_in[4];
    const float* mean    = (const float*)d_in[5];
    const float* var     = (const float*)d_in[6];
    float* out = (float*)d_out;

    char* ws = (char*)d_ws;
    unsigned short* btab  = (unsigned short*)(ws + WS_BTAB);
    float*          shift = (float*)(ws + WS_SHIFT);
    int*            winner = (int*)(ws + WS_WIN);
    float*          feat_ws = (float*)(ws + WS_FEAT);

    const bool compact = ws_size >= WS_NEED;   // constant per session -> graph-safe

    hipMemsetAsync(winner, 0xFF, (size_t)NB * NCELL * sizeof(int), stream);
    winner_prep_kernel<<<(NB * NP + 255) / 256, 256, 0, stream>>>(
        idx, winner, conv_w, gamma, beta, mean, var, btab, shift);

    if (compact) {
        feat_mfma_kernel<true><<<NCHUNK, 256, 0, stream>>>(
            pillars, idx, btab, shift, winner, feat_ws, out);
        scatter_kernel<<<(NB * (NCELL / 4) + 255) / 256, 256, 0, stream>>>(
            winner, feat_ws, out);
    } else {
        hipMemsetAsync(out, 0, (size_t)out_size * sizeof(float), stream);
        feat_mfma_kernel<false><<<NCHUNK, 256, 0, stream>>>(
            pillars, idx, btab, shift, winner, feat_ws, out);
    }
}

// Round 5
// 210.133 us; speedup vs baseline: 1.2814x; 1.0043x over previous
//
#include <hip/hip_runtime.h>
#include <hip/hip_bf16.h>
#include <stdint.h>

#define NB 8
#define NP 12000
#define NM 32
#define NF 9
#define NC 64
#define NX 144
#define NCELL (144*144)

#define PPW 8                        // pillars per wave
#define FEAT_WAVES ((NB*NP)/PPW)     // 12000
#define FEAT_BLOCKS (FEAT_WAVES/4)   // 3000 blocks x 4 waves

typedef __attribute__((ext_vector_type(8)))  short bfrag8;    // 8 bf16
typedef __attribute__((ext_vector_type(16))) float accf16;    // 16 f32 acc

// ws layout:
//   [0,2048)        btab: 2 c-tiles x 64 lanes x 8 bf16 (B-frag order, BN-folded)
//   [2048,2304)     shift[c]
//   [4096,667648)   winner[b][cell] (8*20736 ints)
//   [668672,+24.576M) feat_ws[(b*NP+p)*64 + c]
#define WS_BTAB  0
#define WS_SHIFT 2048
#define WS_WIN   4096
#define WS_FEAT  668672
#define WS_NEED  (WS_FEAT + (size_t)NB*NP*NC*4)

// Pass 1: last-write-wins winner (largest p wins, numpy fancy-assign) +
// BN-folded weight table prep in block 0.
// btab[ct][lane] = B[k=(lane>>5)*8+j][col=lane&31], c=ct*32+col, k>=9 zeroed.
__global__ void winner_prep_kernel(const int* __restrict__ idx, int* __restrict__ winner,
                                   const float* __restrict__ conv_w,
                                   const float* __restrict__ gamma,
                                   const float* __restrict__ beta,
                                   const float* __restrict__ mean,
                                   const float* __restrict__ var,
                                   unsigned short* __restrict__ btab,
                                   float* __restrict__ shift)
{
    int t = blockIdx.x * blockDim.x + threadIdx.x;
    if (t < NB * NP) {
        int b = t / NP;
        int p = t - b * NP;
        int y = idx[t * 3 + 1];
        int x = idx[t * 3 + 2];
        x = x < 0 ? 0 : (x > 143 ? 143 : x);
        y = y < 0 ? 0 : (y > 143 ? 143 : y);
        atomicMax(&winner[b * NCELL + y * NX + x], p);   // init = -1
    }
    if (blockIdx.x == 0) {
        int tt = threadIdx.x;
        if (tt < 128) {
            int ct = tt >> 6, L = tt & 63;
            int c  = ct * 32 + (L & 31);
            int kq = L >> 5;
            float sc = gamma[c] * rsqrtf(var[c] + 1e-5f);
            unsigned short* dst = btab + (ct * 64 + L) * 8;
            #pragma unroll
            for (int j = 0; j < 8; ++j) {
                int k = kq * 8 + j;
                float w = (k < NF) ? conv_w[c * NF + k] * sc : 0.f;
                __hip_bfloat16 h = __float2bfloat16(w);
                dst[j] = *(unsigned short*)&h;
            }
        }
        if (tt < NC) {
            float sc = gamma[tt] * rsqrtf(var[tt] + 1e-5f);
            shift[tt] = beta[tt] - mean[tt] * sc;
        }
    }
}

// Pass 2: dense streaming conv+max over ALL pillars. No LDS, no barrier, no
// winner/idx dependence (compact path) -> fully pipelinable. Lane L loads row
// (L&31)'s 9 floats straight from global (whole wave touches one contiguous
// 1152B pillar block -> L1-coalesced), builds the 32x32x16 A-frag in-register,
// 2 MFMA (c-tiles of 32), max over m = 15 reg-max + shfl_xor(32), BN shift +
// relu, 256B coalesced store to feat_ws.
template <bool COMPACT>
__global__ void __launch_bounds__(256) feat_dense_kernel(
    const float* __restrict__ pillars,
    const unsigned short* __restrict__ btab,
    const float* __restrict__ shift,
    const int*   __restrict__ idx,       // fallback path only
    const int*   __restrict__ winner,    // fallback path only
    float* __restrict__ feat_ws,
    float* __restrict__ out)
{
    int tid  = threadIdx.x;
    int lane = tid & 63;
    int wave = blockIdx.x * 4 + (tid >> 6);
    int row  = lane & 31;
    int kq   = lane >> 5;

    bfrag8 b0 = *(const bfrag8*)(btab + lane * 8);          // c 0..31
    bfrag8 b1 = *(const bfrag8*)(btab + (64 + lane) * 8);   // c 32..63
    float  sh = shift[lane];
    accf16 z  = {};   // zero acc input, hoisted

    #pragma unroll 2
    for (int i = 0; i < PPW; ++i) {
        int pil = wave * PPW + i;
        const float* base = pillars + (size_t)pil * (NM * NF) + row * NF;
        float f[9];
        #pragma unroll
        for (int j = 0; j < 9; ++j) f[j] = base[j];   // always in-bounds (row*9+8<=287)
        // A-frag: kq=0 -> f0..7 ; kq=1 -> {f8, 0...}
        bfrag8 a;
        #pragma unroll
        for (int j = 0; j < 8; ++j) {
            float g = kq ? (j == 0 ? f[8] : 0.f) : f[j];
            __hip_bfloat16 h = __float2bfloat16(g);
            a[j] = *(short*)&h;
        }
        accf16 acc0 = __builtin_amdgcn_mfma_f32_32x32x16_bf16(a, b0, z, 0, 0, 0);
        accf16 acc1 = __builtin_amdgcn_mfma_f32_32x32x16_bf16(a, b1, z, 0, 0, 0);

        float v0 = acc0[0], v1 = acc1[0];
        #pragma unroll
        for (int j = 1; j < 16; ++j) { v0 = fmaxf(v0, acc0[j]); v1 = fmaxf(v1, acc1[j]); }
        v0 = fmaxf(v0, __shfl_xor(v0, 32));
        v1 = fmaxf(v1, __shfl_xor(v1, 32));
        float r = (lane < 32) ? v0 : v1;    // col=lane&31 -> channel = lane
        r += sh;
        r = r > 0.f ? r : 0.f;

        if (COMPACT) {
            feat_ws[(size_t)pil * NC + lane] = r;
        } else {
            int b = pil / NP, p = pil - b * NP;
            int y = idx[pil * 3 + 1], x = idx[pil * 3 + 2];
            x = x < 0 ? 0 : (x > 143 ? 143 : x);
            y = y < 0 ? 0 : (y > 143 ? 143 : y);
            int cell = y * NX + x;
            if (winner[b * NCELL + cell] == p)
                out[((size_t)(b * NC + lane)) * NCELL + cell] = r;
        }
    }
}

// Pass 3: cell-major coalesced canvas write. thread = (b, channel-quarter q,
// 4 consecutive cells): 16 float4 LLC gathers + 16 coalesced float4 stores.
// 4x the thread count of R3's version -> 4x memory-level parallelism.
__global__ void __launch_bounds__(256) scatter_kernel(
    const int* __restrict__ winner,
    const float* __restrict__ feat_ws,
    float* __restrict__ out)
{
    int t  = blockIdx.x * blockDim.x + threadIdx.x;   // [0, NB*4*(NCELL/4))
    int c4 = t % (NCELL / 4);
    int bq = t / (NCELL / 4);
    int q  = bq & 3;
    int b  = bq >> 2;
    int cellbase = c4 * 4;

    int4 wv = *(const int4*)(winner + b * NCELL + cellbase);
    long long base0 = wv.x < 0 ? -1 : ((long long)(b * NP + wv.x)) * NC;
    long long base1 = wv.y < 0 ? -1 : ((long long)(b * NP + wv.y)) * NC;
    long long base2 = wv.z < 0 ? -1 : ((long long)(b * NP + wv.z)) * NC;
    long long base3 = wv.w < 0 ? -1 : ((long long)(b * NP + wv.w)) * NC;

    const float4 zf = make_float4(0.f, 0.f, 0.f, 0.f);
    #pragma unroll
    for (int k = 0; k < 4; ++k) {
        int c0 = q * 16 + k * 4;
        float4 f0 = base0 < 0 ? zf : *(const float4*)(feat_ws + base0 + c0);
        float4 f1 = base1 < 0 ? zf : *(const float4*)(feat_ws + base1 + c0);
        float4 f2 = base2 < 0 ? zf : *(const float4*)(feat_ws + base2 + c0);
        float4 f3 = base3 < 0 ? zf : *(const float4*)(feat_ws + base3 + c0);
        float* o = out + ((size_t)(b * NC + c0)) * NCELL + cellbase;
        *(float4*)(o + 0ULL * NCELL) = make_float4(f0.x, f1.x, f2.x, f3.x);
        *(float4*)(o + 1ULL * NCELL) = make_float4(f0.y, f1.y, f2.y, f3.y);
        *(float4*)(o + 2ULL * NCELL) = make_float4(f0.z, f1.z, f2.z, f3.z);
        *(float4*)(o + 3ULL * NCELL) = make_float4(f0.w, f1.w, f2.w, f3.w);
    }
}

extern "C" void kernel_launch(void* const* d_in, const int* in_sizes, int n_in,
                              void* d_out, int out_size, void* d_ws, size_t ws_size,
                              hipStream_t stream) {
    const float* pillars = (const float*)d_in[0];
    const int*   idx     = (const int*)d_in[1];
    const float* conv_w  = (const float*)d_in[2];
    const float* gamma   = (const float*)d_in[3];
    const float* beta    = (const float*)d_in[4];
    const float* mean    = (const float*)d_in[5];
    const float* var     = (const float*)d_in[6];
    float* out = (float*)d_out;

    char* ws = (char*)d_ws;
    unsigned short* btab    = (unsigned short*)(ws + WS_BTAB);
    float*          shift   = (float*)(ws + WS_SHIFT);
    int*            winner  = (int*)(ws + WS_WIN);
    float*          feat_ws = (float*)(ws + WS_FEAT);

    const bool compact = ws_size >= WS_NEED;   // constant per session -> graph-safe

    hipMemsetAsync(winner, 0xFF, (size_t)NB * NCELL * sizeof(int), stream);
    winner_prep_kernel<<<(NB * NP + 255) / 256, 256, 0, stream>>>(
        idx, winner, conv_w, gamma, beta, mean, var, btab, shift);

    if (compact) {
        feat_dense_kernel<true><<<FEAT_BLOCKS, 256, 0, stream>>>(
            pillars, btab, shift, idx, winner, feat_ws, out);
        int sthreads = NB * 4 * (NCELL / 4);             // 165,888 = 648 blocks
        scatter_kernel<<<sthreads / 256, 256, 0, stream>>>(winner, feat_ws, out);
    } else {
        hipMemsetAsync(out, 0, (size_t)out_size * sizeof(float), stream);
        feat_dense_kernel<false><<<FEAT_BLOCKS, 256, 0, stream>>>(
            pillars, btab, shift, idx, winner, feat_ws, out);
    }
}